// Round 1
// baseline (740.982 us; speedup 1.0000x reference)
//
#include <hip/hip_runtime.h>
#include <math.h>

namespace {

constexpr int B    = 512;
constexpr int IN   = 2048;
constexpr int HID  = 4096;
constexpr int NBLK = 64;      // router blocks
constexpr int NNZ_W = 83886;
constexpr int NNZ_R = 167772;
constexpr float DT = 0.1f;

// ---------------------------------------------------------------------------
// Tiled transpose: src[R][C] -> dst[C][R].  R, C multiples of TILE.
// ---------------------------------------------------------------------------
template <int TILE>
__global__ void transpose_k(const float* __restrict__ src, float* __restrict__ dst,
                            int R, int C) {
  __shared__ float t[TILE][TILE + 1];
  const int bx = blockIdx.x * TILE;  // src col base
  const int by = blockIdx.y * TILE;  // src row base
  const int tx = threadIdx.x;
  for (int i = threadIdx.y; i < TILE; i += blockDim.y)
    t[i][tx] = src[(size_t)(by + i) * C + bx + tx];
  __syncthreads();
  for (int i = threadIdx.y; i < TILE; i += blockDim.y)
    dst[(size_t)(bx + i) * R + by + tx] = t[tx][i];
}

// ---------------------------------------------------------------------------
// Router: rgT[o][b] = sigmoid(sum_k x[b][k] * rw[o][k] + rb[o])
// One block per batch row; x row staged in LDS; 256 thr = 64 outputs x 4 partials.
// ---------------------------------------------------------------------------
__global__ void router_k(const float* __restrict__ x, const float* __restrict__ rw,
                         const float* __restrict__ rb, float* __restrict__ rgT) {
  __shared__ float xs[IN];
  const int b = blockIdx.x;
  for (int k = threadIdx.x; k < IN; k += blockDim.x) xs[k] = x[(size_t)b * IN + k];
  __syncthreads();
  const int o = threadIdx.x >> 2;     // 0..63
  const int q = threadIdx.x & 3;      // 0..3
  const float* w  = rw + (size_t)o * IN + q * (IN / 4);
  const float* xp = xs + q * (IN / 4);
  float s = 0.f;
#pragma unroll 8
  for (int k = 0; k < IN / 4; ++k) s += xp[k] * w[k];
  s += __shfl_xor(s, 1);
  s += __shfl_xor(s, 2);
  if (q == 0) rgT[o * B + b] = 1.f / (1.f + expf(-(s + rb[o])));
}

// ---------------------------------------------------------------------------
// Init accumulators with biases (batch-transposed layout, b fastest).
// ---------------------------------------------------------------------------
__global__ void init_k(float* __restrict__ sensT, float* __restrict__ recT,
                       const float* __restrict__ wb, const float* __restrict__ rbias) {
  const int i = blockIdx.x * blockDim.x + threadIdx.x;  // over HID*B
  const int c = i >> 9;                                 // /B
  sensT[i] = wb[c];
  recT[i]  = rbias[c];
}

// ---------------------------------------------------------------------------
// Edge scatter: outT[cols[e]][b] += srcT[rows[e]][b] * vals[e]
// One 64-lane wave per edge, 4 edges per 256-thread block.
// Both the read and the atomicAdd are 256B-contiguous per wave iteration.
// ---------------------------------------------------------------------------
__global__ void scatter_k(const float* __restrict__ srcT,
                          const int* __restrict__ rows, const int* __restrict__ cols,
                          const float* __restrict__ vals, float* __restrict__ outT,
                          int nnz) {
  const int e = blockIdx.x * 4 + (threadIdx.x >> 6);
  if (e >= nnz) return;
  const int r = rows[e];
  const int c = cols[e];
  const float v = vals[e];
  const int lane = threadIdx.x & 63;
  const float* src = srcT + (size_t)r * B;
  float* dst = outT + (size_t)c * B;
#pragma unroll
  for (int b = lane; b < B; b += 64)
    atomicAdd(&dst[b], src[b] * v);
}

// ---------------------------------------------------------------------------
// Fused mask * sensory + rec -> tanh -> leaky integrate.
// In-place: sens_hn buffer becomes h_newT; rec_pred buffer becomes predT (bias).
// ---------------------------------------------------------------------------
__global__ void combine_k(float* sens_hn, float* rec_pred,
                          const float* __restrict__ hT, const float* __restrict__ rgT,
                          const float* __restrict__ gate, const float* __restrict__ tau,
                          const float* __restrict__ pbias) {
  const int i = blockIdx.x * blockDim.x + threadIdx.x;  // over HID*B, b fastest
  const int c = i >> 9;
  const int b = i & (B - 1);
  const float m   = rgT[(c >> 6) * B + b];
  const float tgt = tanhf(sens_hn[i] * m + rec_pred[i]);
  const float hp  = hT[i];
  const float hn  = hp + gate[b] * (tgt - hp) * (DT / tau[c]);
  sens_hn[i]  = hn;        // becomes h_newT
  rec_pred[i] = pbias[c];  // becomes predT accumulator init
}

}  // namespace

extern "C" void kernel_launch(void* const* d_in, const int* in_sizes, int n_in,
                              void* d_out, int out_size, void* d_ws, size_t ws_size,
                              hipStream_t stream) {
  const float* x        = (const float*)d_in[0];
  const float* h_prev   = (const float*)d_in[1];
  const float* gate     = (const float*)d_in[2];
  const float* W_vals   = (const float*)d_in[3];
  const float* W_bias   = (const float*)d_in[4];
  const float* R_vals   = (const float*)d_in[5];
  const float* R_bias   = (const float*)d_in[6];
  const float* P_vals   = (const float*)d_in[7];
  const float* P_bias   = (const float*)d_in[8];
  const float* router_w = (const float*)d_in[9];
  const float* router_b = (const float*)d_in[10];
  const float* tau      = (const float*)d_in[11];
  const int* W_rows = (const int*)d_in[12];
  const int* W_cols = (const int*)d_in[13];
  const int* R_rows = (const int*)d_in[14];
  const int* R_cols = (const int*)d_in[15];
  const int* P_rows = (const int*)d_in[16];
  const int* P_cols = (const int*)d_in[17];

  // Workspace layout (floats). Buffers reused in-place after combine_k:
  //   sensT -> h_newT, recT -> predT.  Total ~29.5 MB.
  float* ws    = (float*)d_ws;
  float* xT    = ws;                  // [IN][B]   4 MB
  float* hT    = xT + (size_t)IN * B; // [HID][B]  8 MB
  float* rgT   = hT + (size_t)HID * B;// [NBLK][B] 128 KB
  float* sensT = rgT + NBLK * B;      // [HID][B]  8 MB (-> h_newT)
  float* recT  = sensT + (size_t)HID * B; // [HID][B] 8 MB (-> predT)

  float* out_h = (float*)d_out;               // [B][HID]
  float* out_p = out_h + (size_t)B * HID;     // [B][HID]

  const dim3 tb(64, 8);

  // 1. Batch-transpose inputs for coalesced per-edge access.
  transpose_k<64><<<dim3(IN / 64, B / 64), tb, 0, stream>>>(x, xT, B, IN);
  transpose_k<64><<<dim3(HID / 64, B / 64), tb, 0, stream>>>(h_prev, hT, B, HID);

  // 2. Router gates (transposed layout).
  router_k<<<B, 256, 0, stream>>>(x, router_w, router_b, rgT);

  // 3. Bias-init accumulators.
  init_k<<<(HID * B) / 256, 256, 0, stream>>>(sensT, recT, W_bias, R_bias);

  // 4. Sparse scatters: sensory (from x) and recurrent (from h_prev).
  scatter_k<<<(NNZ_W + 3) / 4, 256, 0, stream>>>(xT, W_rows, W_cols, W_vals, sensT, NNZ_W);
  scatter_k<<<(NNZ_R + 3) / 4, 256, 0, stream>>>(hT, R_rows, R_cols, R_vals, recT, NNZ_R);

  // 5. Fuse mask/tanh/integration; buffers become h_newT and predT(bias).
  combine_k<<<(HID * B) / 256, 256, 0, stream>>>(sensT, recT, hT, rgT, gate, tau, P_bias);

  // 6. Prediction scatter from h_new.
  scatter_k<<<(NNZ_R + 3) / 4, 256, 0, stream>>>(sensT, P_rows, P_cols, P_vals, recT, NNZ_R);

  // 7. Transpose results to row-major outputs.
  transpose_k<64><<<dim3(B / 64, HID / 64), tb, 0, stream>>>(sensT, out_h, HID, B);
  transpose_k<64><<<dim3(B / 64, HID / 64), tb, 0, stream>>>(recT, out_p, HID, B);
}

// Round 4
// 212.664 us; speedup vs baseline: 3.4843x; 3.4843x over previous
//
// Retry of round-2 design (sort+gather, no fp atomics) — previous two rounds
// failed on container infrastructure before executing.
#include <hip/hip_runtime.h>
#include <math.h>

namespace {

constexpr int B     = 512;
constexpr int IN    = 2048;
constexpr int HID   = 4096;
constexpr int NNZ_W = 83886;
constexpr int NNZ_R = 167772;
constexpr int NTOT  = NNZ_W + 2 * NNZ_R;   // 419430 edges across W,R,P
constexpr int NCOLS = 3 * HID;             // global column id = mat*HID + col
constexpr float DT  = 0.1f;

// ---------------------------------------------------------------------------
// Tiled transpose: src[R][C] -> dst[C][R].  R, C multiples of TILE.
// ---------------------------------------------------------------------------
template <int TILE>
__global__ void transpose_k(const float* __restrict__ src, float* __restrict__ dst,
                            int R, int C) {
  __shared__ float t[TILE][TILE + 1];
  const int bx = blockIdx.x * TILE;
  const int by = blockIdx.y * TILE;
  const int tx = threadIdx.x;
  for (int i = threadIdx.y; i < TILE; i += blockDim.y)
    t[i][tx] = src[(size_t)(by + i) * C + bx + tx];
  __syncthreads();
  for (int i = threadIdx.y; i < TILE; i += blockDim.y)
    dst[(size_t)(bx + i) * R + by + tx] = t[tx][i];
}

// ---------------------------------------------------------------------------
// Router: rgT[o][b] = sigmoid(sum_k x[b][k] * rw[o][k] + rb[o])
// ---------------------------------------------------------------------------
__global__ void router_k(const float* __restrict__ x, const float* __restrict__ rw,
                         const float* __restrict__ rb, float* __restrict__ rgT) {
  __shared__ float xs[IN];
  const int b = blockIdx.x;
  for (int k = threadIdx.x; k < IN; k += blockDim.x) xs[k] = x[(size_t)b * IN + k];
  __syncthreads();
  const int o = threadIdx.x >> 2;
  const int q = threadIdx.x & 3;
  const float* w  = rw + (size_t)o * IN + q * (IN / 4);
  const float* xp = xs + q * (IN / 4);
  float s = 0.f;
#pragma unroll 8
  for (int k = 0; k < IN / 4; ++k) s += xp[k] * w[k];
  s += __shfl_xor(s, 1);
  s += __shfl_xor(s, 2);
  if (q == 0) rgT[o * B + b] = 1.f / (1.f + expf(-(s + rb[o])));
}

// ---------------------------------------------------------------------------
// Edge binning: histogram -> scan -> counting-sort into column-major edge list.
// ---------------------------------------------------------------------------
__global__ void zero_k(int* __restrict__ cnt) {
  const int i = blockIdx.x * blockDim.x + threadIdx.x;
  if (i < NCOLS) cnt[i] = 0;
}

__global__ void hist_k(const int* __restrict__ Wc, const int* __restrict__ Rc,
                       const int* __restrict__ Pc, int* __restrict__ cnt) {
  const int i = blockIdx.x * blockDim.x + threadIdx.x;
  if (i >= NTOT) return;
  int gc;
  if (i < NNZ_W)              gc = Wc[i];
  else if (i < NNZ_W + NNZ_R) gc = HID + Rc[i - NNZ_W];
  else                        gc = 2 * HID + Pc[i - NNZ_W - NNZ_R];
  atomicAdd(&cnt[gc], 1);
}

// Single-block exclusive scan of cnt[NCOLS] -> offs, cur.
__global__ void scan_k(const int* __restrict__ cnt, int* __restrict__ offs,
                       int* __restrict__ cur) {
  __shared__ int ps[1024];
  const int t = threadIdx.x;
  int loc[12];
  int tot = 0;
#pragma unroll
  for (int j = 0; j < 12; ++j) { loc[j] = tot; tot += cnt[t * 12 + j]; }
  ps[t] = tot;
  __syncthreads();
  for (int d = 1; d < 1024; d <<= 1) {
    int v = (t >= d) ? ps[t - d] : 0;
    __syncthreads();
    ps[t] += v;
    __syncthreads();
  }
  const int base = ps[t] - tot;
#pragma unroll
  for (int j = 0; j < 12; ++j) {
    const int o = base + loc[j];
    offs[t * 12 + j] = o;
    cur[t * 12 + j]  = o;
  }
}

// packed[p] = (val, row_bits), sorted by global column.
__global__ void sortscat_k(const int* __restrict__ Wc, const int* __restrict__ Rc,
                           const int* __restrict__ Pc, const int* __restrict__ Wr,
                           const int* __restrict__ Rr, const int* __restrict__ Pr,
                           const float* __restrict__ Wv, const float* __restrict__ Rv,
                           const float* __restrict__ Pv, int* __restrict__ cur,
                           float2* __restrict__ packed) {
  const int i = blockIdx.x * blockDim.x + threadIdx.x;
  if (i >= NTOT) return;
  int gc, r; float v;
  if (i < NNZ_W)              { gc = Wc[i];                  r = Wr[i]; v = Wv[i]; }
  else if (i < NNZ_W + NNZ_R) { int j = i - NNZ_W;           gc = HID + Rc[j];     r = Rr[j]; v = Rv[j]; }
  else                        { int j = i - NNZ_W - NNZ_R;  gc = 2 * HID + Pc[j]; r = Pr[j]; v = Pv[j]; }
  const int p = atomicAdd(&cur[gc], 1);
  packed[p] = make_float2(v, __int_as_float(r));
}

// ---------------------------------------------------------------------------
// Column gather: acc[b] = bias + sum_e val_e * srcT[row_e][b].
// One wave per (column, 256-batch chunk); each lane owns 4 consecutive b.
// ---------------------------------------------------------------------------
__device__ __forceinline__ float4 gather_col(const float* __restrict__ srcT,
                                             const float2* __restrict__ packed,
                                             int beg, int n, int boff, float bias) {
  float4 acc = make_float4(bias, bias, bias, bias);
  const float2* ep = packed + beg;
  for (int i = 0; i < n; ++i) {
    const float2 e = ep[i];
    const int r = __float_as_int(e.y);
    const float4 s = *(const float4*)(srcT + (size_t)r * B + boff);
    acc.x += e.x * s.x; acc.y += e.x * s.y; acc.z += e.x * s.z; acc.w += e.x * s.w;
  }
  return acc;
}

// ---------------------------------------------------------------------------
// Fused: sensory gather (W) * mask + recurrent gather (R) -> tanh -> integrate.
// ---------------------------------------------------------------------------
__global__ void fused_gc_k(const float* __restrict__ xT, const float* __restrict__ hT,
                           const float2* __restrict__ packed, const int* __restrict__ offs,
                           const int* __restrict__ cnt, const float* __restrict__ rgT,
                           const float* __restrict__ gate, const float* __restrict__ tau,
                           const float* __restrict__ wb, const float* __restrict__ rb,
                           float* __restrict__ hnT) {
  const int w = blockIdx.x * (blockDim.x >> 6) + (threadIdx.x >> 6);
  const int c = w >> 1;
  const int boff = (w & 1) * 256 + (threadIdx.x & 63) * 4;

  const float4 sens = gather_col(xT, packed, offs[c], cnt[c], boff, wb[c]);
  const float4 rec  = gather_col(hT, packed, offs[HID + c], cnt[HID + c], boff, rb[c]);

  const float4 m  = *(const float4*)(rgT + (size_t)(c >> 6) * B + boff);
  const float4 g  = *(const float4*)(gate + boff);
  const float4 hp = *(const float4*)(hT + (size_t)c * B + boff);
  const float k = DT / tau[c];
  float4 hn;
  hn.x = hp.x + g.x * (tanhf(sens.x * m.x + rec.x) - hp.x) * k;
  hn.y = hp.y + g.y * (tanhf(sens.y * m.y + rec.y) - hp.y) * k;
  hn.z = hp.z + g.z * (tanhf(sens.z * m.z + rec.z) - hp.z) * k;
  hn.w = hp.w + g.w * (tanhf(sens.w * m.w + rec.w) - hp.w) * k;
  *(float4*)(hnT + (size_t)c * B + boff) = hn;
}

// ---------------------------------------------------------------------------
// Prediction gather from h_new.
// ---------------------------------------------------------------------------
__global__ void pred_k(const float* __restrict__ hnT, const float2* __restrict__ packed,
                       const int* __restrict__ offs, const int* __restrict__ cnt,
                       const float* __restrict__ pb, float* __restrict__ predT) {
  const int w = blockIdx.x * (blockDim.x >> 6) + (threadIdx.x >> 6);
  const int c = w >> 1;
  const int boff = (w & 1) * 256 + (threadIdx.x & 63) * 4;
  const float4 p = gather_col(hnT, packed, offs[2 * HID + c], cnt[2 * HID + c], boff, pb[c]);
  *(float4*)(predT + (size_t)c * B + boff) = p;
}

}  // namespace

extern "C" void kernel_launch(void* const* d_in, const int* in_sizes, int n_in,
                              void* d_out, int out_size, void* d_ws, size_t ws_size,
                              hipStream_t stream) {
  const float* x        = (const float*)d_in[0];
  const float* h_prev   = (const float*)d_in[1];
  const float* gate     = (const float*)d_in[2];
  const float* W_vals   = (const float*)d_in[3];
  const float* W_bias   = (const float*)d_in[4];
  const float* R_vals   = (const float*)d_in[5];
  const float* R_bias   = (const float*)d_in[6];
  const float* P_vals   = (const float*)d_in[7];
  const float* P_bias   = (const float*)d_in[8];
  const float* router_w = (const float*)d_in[9];
  const float* router_b = (const float*)d_in[10];
  const float* tau      = (const float*)d_in[11];
  const int* W_rows = (const int*)d_in[12];
  const int* W_cols = (const int*)d_in[13];
  const int* R_rows = (const int*)d_in[14];
  const int* R_cols = (const int*)d_in[15];
  const int* P_rows = (const int*)d_in[16];
  const int* P_cols = (const int*)d_in[17];

  // Workspace layout (float units).  predT reuses the dead xT+hT region.
  float* ws = (float*)d_ws;
  float*  xT     = ws;                               // [IN][B]    4 MB
  float*  hT     = xT + (size_t)IN * B;              // [HID][B]   8 MB
  float*  rgT    = hT + (size_t)HID * B;             // [64][B]    128 KB
  float*  hnT    = rgT + 64 * B;                     // [HID][B]   8 MB
  float2* packed = (float2*)(hnT + (size_t)HID * B); // [NTOT]     3.4 MB
  int*    cnt    = (int*)(packed + NTOT);            // [NCOLS]
  int*    offs   = cnt + NCOLS;                      // [NCOLS]
  int*    cur    = offs + NCOLS;                     // [NCOLS]
  float*  predT  = ws;                               // [HID][B]   8 MB (reuse)

  float* out_h = (float*)d_out;
  float* out_p = out_h + (size_t)B * HID;

  const dim3 tb(64, 8);

  // 1. Batch-transpose inputs (coalesced per-edge access).
  transpose_k<64><<<dim3(IN / 64, B / 64), tb, 0, stream>>>(x, xT, B, IN);
  transpose_k<64><<<dim3(HID / 64, B / 64), tb, 0, stream>>>(h_prev, hT, B, HID);

  // 2. Router gates.
  router_k<<<B, 256, 0, stream>>>(x, router_w, router_b, rgT);

  // 3. Bin edges by output column (counting sort) -> gather form, no fp atomics.
  zero_k<<<NCOLS / 256, 256, 0, stream>>>(cnt);
  hist_k<<<(NTOT + 255) / 256, 256, 0, stream>>>(W_cols, R_cols, P_cols, cnt);
  scan_k<<<1, 1024, 0, stream>>>(cnt, offs, cur);
  sortscat_k<<<(NTOT + 255) / 256, 256, 0, stream>>>(W_cols, R_cols, P_cols,
                                                     W_rows, R_rows, P_rows,
                                                     W_vals, R_vals, P_vals, cur, packed);

  // 4. Fused sensory+recurrent gather, mask, tanh, leaky integrate -> hnT.
  fused_gc_k<<<HID * 2 / 4, 256, 0, stream>>>(xT, hT, packed, offs, cnt, rgT,
                                              gate, tau, W_bias, R_bias, hnT);

  // 5. Prediction gather from h_new -> predT (reuses xT/hT space).
  pred_k<<<HID * 2 / 4, 256, 0, stream>>>(hnT, packed, offs, cnt, P_bias, predT);

  // 6. Transpose to row-major outputs.
  transpose_k<64><<<dim3(B / 64, HID / 64), tb, 0, stream>>>(hnT, out_h, HID, B);
  transpose_k<64><<<dim3(B / 64, HID / 64), tb, 0, stream>>>(predT, out_p, HID, B);
}

// Round 5
// 193.060 us; speedup vs baseline: 3.8381x; 1.1015x over previous
//
// Sort+gather + batched-MLP gather loops (4 edges in flight) + merged transposes.
#include <hip/hip_runtime.h>
#include <math.h>

namespace {

constexpr int B     = 512;
constexpr int IN    = 2048;
constexpr int HID   = 4096;
constexpr int NNZ_W = 83886;
constexpr int NNZ_R = 167772;
constexpr int NTOT  = NNZ_W + 2 * NNZ_R;   // 419430 edges across W,R,P
constexpr int NCOLS = 3 * HID;             // global column id = mat*HID + col
constexpr float DT  = 0.1f;

// ---------------------------------------------------------------------------
// Paired tiled transpose: two independent [R][C] -> [C][R] jobs in one launch.
// ---------------------------------------------------------------------------
__global__ void transpose2_k(const float* __restrict__ sA, float* __restrict__ dA,
                             int RA, int CA, int tilesA,
                             const float* __restrict__ sB, float* __restrict__ dB,
                             int RB, int CB) {
  __shared__ float t[64][65];
  int tb = blockIdx.x;
  const float* src; float* dst; int R, C;
  if (tb < tilesA) { src = sA; dst = dA; R = RA; C = CA; }
  else             { tb -= tilesA; src = sB; dst = dB; R = RB; C = CB; }
  const int tx_n = C / 64;
  const int bx = (tb % tx_n) * 64;
  const int by = (tb / tx_n) * 64;
  const int tx = threadIdx.x;
  for (int i = threadIdx.y; i < 64; i += blockDim.y)
    t[i][tx] = src[(size_t)(by + i) * C + bx + tx];
  __syncthreads();
  for (int i = threadIdx.y; i < 64; i += blockDim.y)
    dst[(size_t)(bx + i) * R + by + tx] = t[tx][i];
}

// ---------------------------------------------------------------------------
// Router: rgT[o][b] = sigmoid(sum_k x[b][k] * rw[o][k] + rb[o])
// ---------------------------------------------------------------------------
__global__ void router_k(const float* __restrict__ x, const float* __restrict__ rw,
                         const float* __restrict__ rb, float* __restrict__ rgT) {
  __shared__ float xs[IN];
  const int b = blockIdx.x;
  for (int k = threadIdx.x; k < IN; k += blockDim.x) xs[k] = x[(size_t)b * IN + k];
  __syncthreads();
  const int o = threadIdx.x >> 2;
  const int q = threadIdx.x & 3;
  const float* w  = rw + (size_t)o * IN + q * (IN / 4);
  const float* xp = xs + q * (IN / 4);
  float s = 0.f;
#pragma unroll 8
  for (int k = 0; k < IN / 4; ++k) s += xp[k] * w[k];
  s += __shfl_xor(s, 1);
  s += __shfl_xor(s, 2);
  if (q == 0) rgT[o * B + b] = 1.f / (1.f + expf(-(s + rb[o])));
}

// ---------------------------------------------------------------------------
// Edge binning: histogram -> scan -> counting-sort into column-major edge list.
// ---------------------------------------------------------------------------
__global__ void zero_k(int* __restrict__ cnt) {
  const int i = blockIdx.x * blockDim.x + threadIdx.x;
  if (i < NCOLS) cnt[i] = 0;
}

__global__ void hist_k(const int* __restrict__ Wc, const int* __restrict__ Rc,
                       const int* __restrict__ Pc, int* __restrict__ cnt) {
  const int i = blockIdx.x * blockDim.x + threadIdx.x;
  if (i >= NTOT) return;
  int gc;
  if (i < NNZ_W)              gc = Wc[i];
  else if (i < NNZ_W + NNZ_R) gc = HID + Rc[i - NNZ_W];
  else                        gc = 2 * HID + Pc[i - NNZ_W - NNZ_R];
  atomicAdd(&cnt[gc], 1);
}

// Single-block exclusive scan of cnt[NCOLS] -> offs, cur.
__global__ void scan_k(const int* __restrict__ cnt, int* __restrict__ offs,
                       int* __restrict__ cur) {
  __shared__ int ps[1024];
  const int t = threadIdx.x;
  int loc[12];
  int tot = 0;
#pragma unroll
  for (int j = 0; j < 12; ++j) { loc[j] = tot; tot += cnt[t * 12 + j]; }
  ps[t] = tot;
  __syncthreads();
  for (int d = 1; d < 1024; d <<= 1) {
    int v = (t >= d) ? ps[t - d] : 0;
    __syncthreads();
    ps[t] += v;
    __syncthreads();
  }
  const int base = ps[t] - tot;
#pragma unroll
  for (int j = 0; j < 12; ++j) {
    const int o = base + loc[j];
    offs[t * 12 + j] = o;
    cur[t * 12 + j]  = o;
  }
}

// packed[p] = (val, row_bits), sorted by global column.
__global__ void sortscat_k(const int* __restrict__ Wc, const int* __restrict__ Rc,
                           const int* __restrict__ Pc, const int* __restrict__ Wr,
                           const int* __restrict__ Rr, const int* __restrict__ Pr,
                           const float* __restrict__ Wv, const float* __restrict__ Rv,
                           const float* __restrict__ Pv, int* __restrict__ cur,
                           float2* __restrict__ packed) {
  const int i = blockIdx.x * blockDim.x + threadIdx.x;
  if (i >= NTOT) return;
  int gc, r; float v;
  if (i < NNZ_W)              { gc = Wc[i];                 r = Wr[i]; v = Wv[i]; }
  else if (i < NNZ_W + NNZ_R) { int j = i - NNZ_W;          gc = HID + Rc[j];     r = Rr[j]; v = Rv[j]; }
  else                        { int j = i - NNZ_W - NNZ_R; gc = 2 * HID + Pc[j]; r = Pr[j]; v = Pv[j]; }
  const int p = atomicAdd(&cur[gc], 1);
  packed[p] = make_float2(v, __int_as_float(r));
}

// ---------------------------------------------------------------------------
// Column gather, 4 edges in flight: acc[b] = bias + sum_e val_e * srcT[row_e][b].
// One wave per (column, 256-batch chunk); each lane owns 4 consecutive b.
// Accumulation order matches the sequential version (same rounding).
// ---------------------------------------------------------------------------
__device__ __forceinline__ float4 gather_col(const float* __restrict__ srcT,
                                             const float2* __restrict__ packed,
                                             int beg, int n, int boff, float bias) {
  float4 acc = make_float4(bias, bias, bias, bias);
  const float2* ep = packed + beg;
  int i = 0;
  for (; i + 4 <= n; i += 4) {
    const float2 e0 = ep[i + 0];
    const float2 e1 = ep[i + 1];
    const float2 e2 = ep[i + 2];
    const float2 e3 = ep[i + 3];
    const float4 s0 = *(const float4*)(srcT + (size_t)__float_as_int(e0.y) * B + boff);
    const float4 s1 = *(const float4*)(srcT + (size_t)__float_as_int(e1.y) * B + boff);
    const float4 s2 = *(const float4*)(srcT + (size_t)__float_as_int(e2.y) * B + boff);
    const float4 s3 = *(const float4*)(srcT + (size_t)__float_as_int(e3.y) * B + boff);
    acc.x += e0.x * s0.x; acc.y += e0.x * s0.y; acc.z += e0.x * s0.z; acc.w += e0.x * s0.w;
    acc.x += e1.x * s1.x; acc.y += e1.x * s1.y; acc.z += e1.x * s1.z; acc.w += e1.x * s1.w;
    acc.x += e2.x * s2.x; acc.y += e2.x * s2.y; acc.z += e2.x * s2.z; acc.w += e2.x * s2.w;
    acc.x += e3.x * s3.x; acc.y += e3.x * s3.y; acc.z += e3.x * s3.z; acc.w += e3.x * s3.w;
  }
  for (; i < n; ++i) {
    const float2 e = ep[i];
    const float4 s = *(const float4*)(srcT + (size_t)__float_as_int(e.y) * B + boff);
    acc.x += e.x * s.x; acc.y += e.x * s.y; acc.z += e.x * s.z; acc.w += e.x * s.w;
  }
  return acc;
}

// ---------------------------------------------------------------------------
// Fused: sensory gather (W) * mask + recurrent gather (R) -> tanh -> integrate.
// ---------------------------------------------------------------------------
__global__ void fused_gc_k(const float* __restrict__ xT, const float* __restrict__ hT,
                           const float2* __restrict__ packed, const int* __restrict__ offs,
                           const int* __restrict__ cnt, const float* __restrict__ rgT,
                           const float* __restrict__ gate, const float* __restrict__ tau,
                           const float* __restrict__ wb, const float* __restrict__ rb,
                           float* __restrict__ hnT) {
  const int w = blockIdx.x * (blockDim.x >> 6) + (threadIdx.x >> 6);
  const int c = w >> 1;
  const int boff = (w & 1) * 256 + (threadIdx.x & 63) * 4;

  const float4 sens = gather_col(xT, packed, offs[c], cnt[c], boff, wb[c]);
  const float4 rec  = gather_col(hT, packed, offs[HID + c], cnt[HID + c], boff, rb[c]);

  const float4 m  = *(const float4*)(rgT + (size_t)(c >> 6) * B + boff);
  const float4 g  = *(const float4*)(gate + boff);
  const float4 hp = *(const float4*)(hT + (size_t)c * B + boff);
  const float k = DT / tau[c];
  float4 hn;
  hn.x = hp.x + g.x * (tanhf(sens.x * m.x + rec.x) - hp.x) * k;
  hn.y = hp.y + g.y * (tanhf(sens.y * m.y + rec.y) - hp.y) * k;
  hn.z = hp.z + g.z * (tanhf(sens.z * m.z + rec.z) - hp.z) * k;
  hn.w = hp.w + g.w * (tanhf(sens.w * m.w + rec.w) - hp.w) * k;
  *(float4*)(hnT + (size_t)c * B + boff) = hn;
}

// ---------------------------------------------------------------------------
// Prediction gather from h_new.
// ---------------------------------------------------------------------------
__global__ void pred_k(const float* __restrict__ hnT, const float2* __restrict__ packed,
                       const int* __restrict__ offs, const int* __restrict__ cnt,
                       const float* __restrict__ pb, float* __restrict__ predT) {
  const int w = blockIdx.x * (blockDim.x >> 6) + (threadIdx.x >> 6);
  const int c = w >> 1;
  const int boff = (w & 1) * 256 + (threadIdx.x & 63) * 4;
  const float4 p = gather_col(hnT, packed, offs[2 * HID + c], cnt[2 * HID + c], boff, pb[c]);
  *(float4*)(predT + (size_t)c * B + boff) = p;
}

}  // namespace

extern "C" void kernel_launch(void* const* d_in, const int* in_sizes, int n_in,
                              void* d_out, int out_size, void* d_ws, size_t ws_size,
                              hipStream_t stream) {
  const float* x        = (const float*)d_in[0];
  const float* h_prev   = (const float*)d_in[1];
  const float* gate     = (const float*)d_in[2];
  const float* W_vals   = (const float*)d_in[3];
  const float* W_bias   = (const float*)d_in[4];
  const float* R_vals   = (const float*)d_in[5];
  const float* R_bias   = (const float*)d_in[6];
  const float* P_vals   = (const float*)d_in[7];
  const float* P_bias   = (const float*)d_in[8];
  const float* router_w = (const float*)d_in[9];
  const float* router_b = (const float*)d_in[10];
  const float* tau      = (const float*)d_in[11];
  const int* W_rows = (const int*)d_in[12];
  const int* W_cols = (const int*)d_in[13];
  const int* R_rows = (const int*)d_in[14];
  const int* R_cols = (const int*)d_in[15];
  const int* P_rows = (const int*)d_in[16];
  const int* P_cols = (const int*)d_in[17];

  // Workspace layout (float units).  predT reuses the dead xT+hT region.
  float* ws = (float*)d_ws;
  float*  xT     = ws;                               // [IN][B]    4 MB
  float*  hT     = xT + (size_t)IN * B;              // [HID][B]   8 MB
  float*  rgT    = hT + (size_t)HID * B;             // [64][B]    128 KB
  float*  hnT    = rgT + 64 * B;                     // [HID][B]   8 MB
  float2* packed = (float2*)(hnT + (size_t)HID * B); // [NTOT]     3.4 MB
  int*    cnt    = (int*)(packed + NTOT);            // [NCOLS]
  int*    offs   = cnt + NCOLS;                      // [NCOLS]
  int*    cur    = offs + NCOLS;                     // [NCOLS]
  float*  predT  = ws;                               // [HID][B]   8 MB (reuse)

  float* out_h = (float*)d_out;
  float* out_p = out_h + (size_t)B * HID;

  const dim3 tb(64, 8);
  const int tiles_x  = (IN / 64) * (B / 64);    // 256
  const int tiles_h  = (HID / 64) * (B / 64);   // 512
  const int tiles_o  = (B / 64) * (HID / 64);   // 512 per output

  // 1. Batch-transpose both inputs in one launch.
  transpose2_k<<<tiles_x + tiles_h, tb, 0, stream>>>(x, xT, B, IN, tiles_x,
                                                     h_prev, hT, B, HID);

  // 2. Router gates.
  router_k<<<B, 256, 0, stream>>>(x, router_w, router_b, rgT);

  // 3. Bin edges by output column (counting sort) -> gather form, no fp atomics.
  zero_k<<<NCOLS / 256, 256, 0, stream>>>(cnt);
  hist_k<<<(NTOT + 255) / 256, 256, 0, stream>>>(W_cols, R_cols, P_cols, cnt);
  scan_k<<<1, 1024, 0, stream>>>(cnt, offs, cur);
  sortscat_k<<<(NTOT + 255) / 256, 256, 0, stream>>>(W_cols, R_cols, P_cols,
                                                     W_rows, R_rows, P_rows,
                                                     W_vals, R_vals, P_vals, cur, packed);

  // 4. Fused sensory+recurrent gather, mask, tanh, leaky integrate -> hnT.
  fused_gc_k<<<HID * 2 / 4, 256, 0, stream>>>(xT, hT, packed, offs, cnt, rgT,
                                              gate, tau, W_bias, R_bias, hnT);

  // 5. Prediction gather from h_new -> predT (reuses xT/hT space).
  pred_k<<<HID * 2 / 4, 256, 0, stream>>>(hnT, packed, offs, cnt, P_bias, predT);

  // 6. Transpose both results to row-major outputs in one launch.
  transpose2_k<<<2 * tiles_o, tb, 0, stream>>>(hnT, out_h, HID, B, tiles_o,
                                               predT, out_p, HID, B);
}

// Round 6
// 172.218 us; speedup vs baseline: 4.3026x; 1.1210x over previous
//
// Sort+gather; gather SOURCES stored as bf16 (halves L2-miss traffic, the
// measured wall at ~3 TB/s); fp32 accumulation, fp32 h_prev carry path.
#include <hip/hip_runtime.h>
#include <math.h>

namespace {

constexpr int B     = 512;
constexpr int IN    = 2048;
constexpr int HID   = 4096;
constexpr int NNZ_W = 83886;
constexpr int NNZ_R = 167772;
constexpr int NTOT  = NNZ_W + 2 * NNZ_R;   // 419430 edges across W,R,P
constexpr int NCOLS = 3 * HID;             // global column id = mat*HID + col
constexpr float DT  = 0.1f;

struct ushort4_t { unsigned short x, y, z, w; };

__device__ __forceinline__ float bf2f(unsigned short u) {
  return __uint_as_float((unsigned int)u << 16);
}
__device__ __forceinline__ unsigned short f2bf(float f) {  // round-nearest-even
  unsigned int u = __float_as_uint(f);
  u += 0x7FFFu + ((u >> 16) & 1u);
  return (unsigned short)(u >> 16);
}

// ---------------------------------------------------------------------------
// Input transpose: x[B][IN] -> xTb(bf16)[IN][B];  h[B][HID] -> hT(f32)+hTb(bf16).
// ---------------------------------------------------------------------------
__global__ void transpose_in_k(const float* __restrict__ x, unsigned short* __restrict__ xTb,
                               const float* __restrict__ h, float* __restrict__ hT,
                               unsigned short* __restrict__ hTb, int tilesX) {
  __shared__ float t[64][65];
  int tb = blockIdx.x;
  const bool isX = tb < tilesX;
  const float* src; int C;
  if (isX) { src = x; C = IN; } else { tb -= tilesX; src = h; C = HID; }
  const int tx_n = C / 64;
  const int bx = (tb % tx_n) * 64;
  const int by = (tb / tx_n) * 64;
  const int tx = threadIdx.x;
  for (int i = threadIdx.y; i < 64; i += blockDim.y)
    t[i][tx] = src[(size_t)(by + i) * C + bx + tx];
  __syncthreads();
  for (int i = threadIdx.y; i < 64; i += blockDim.y) {
    const float v = t[tx][i];
    const size_t di = (size_t)(bx + i) * B + by + tx;
    if (isX) xTb[di] = f2bf(v);
    else     { hT[di] = v; hTb[di] = f2bf(v); }
  }
}

// ---------------------------------------------------------------------------
// Output transpose: two fp32 [HID][B] -> [B][HID] jobs in one launch.
// ---------------------------------------------------------------------------
__global__ void transpose_out_k(const float* __restrict__ sA, float* __restrict__ dA,
                                int tilesA, const float* __restrict__ sB,
                                float* __restrict__ dB) {
  __shared__ float t[64][65];
  int tb = blockIdx.x;
  const float* src; float* dst;
  if (tb < tilesA) { src = sA; dst = dA; }
  else             { tb -= tilesA; src = sB; dst = dB; }
  const int tx_n = B / 64;                 // src is [HID][B]
  const int bx = (tb % tx_n) * 64;
  const int by = (tb / tx_n) * 64;
  const int tx = threadIdx.x;
  for (int i = threadIdx.y; i < 64; i += blockDim.y)
    t[i][tx] = src[(size_t)(by + i) * B + bx + tx];
  __syncthreads();
  for (int i = threadIdx.y; i < 64; i += blockDim.y)
    dst[(size_t)(bx + i) * HID + by + tx] = t[tx][i];
}

// ---------------------------------------------------------------------------
// Router: rgT[o][b] = sigmoid(sum_k x[b][k] * rw[o][k] + rb[o])
// ---------------------------------------------------------------------------
__global__ void router_k(const float* __restrict__ x, const float* __restrict__ rw,
                         const float* __restrict__ rb, float* __restrict__ rgT) {
  __shared__ float xs[IN];
  const int b = blockIdx.x;
  for (int k = threadIdx.x; k < IN; k += blockDim.x) xs[k] = x[(size_t)b * IN + k];
  __syncthreads();
  const int o = threadIdx.x >> 2;
  const int q = threadIdx.x & 3;
  const float* w  = rw + (size_t)o * IN + q * (IN / 4);
  const float* xp = xs + q * (IN / 4);
  float s = 0.f;
#pragma unroll 8
  for (int k = 0; k < IN / 4; ++k) s += xp[k] * w[k];
  s += __shfl_xor(s, 1);
  s += __shfl_xor(s, 2);
  if (q == 0) rgT[o * B + b] = 1.f / (1.f + expf(-(s + rb[o])));
}

// ---------------------------------------------------------------------------
// Edge binning: histogram -> scan -> counting-sort into column-major edge list.
// ---------------------------------------------------------------------------
__global__ void zero_k(int* __restrict__ cnt) {
  const int i = blockIdx.x * blockDim.x + threadIdx.x;
  if (i < NCOLS) cnt[i] = 0;
}

__global__ void hist_k(const int* __restrict__ Wc, const int* __restrict__ Rc,
                       const int* __restrict__ Pc, int* __restrict__ cnt) {
  const int i = blockIdx.x * blockDim.x + threadIdx.x;
  if (i >= NTOT) return;
  int gc;
  if (i < NNZ_W)              gc = Wc[i];
  else if (i < NNZ_W + NNZ_R) gc = HID + Rc[i - NNZ_W];
  else                        gc = 2 * HID + Pc[i - NNZ_W - NNZ_R];
  atomicAdd(&cnt[gc], 1);
}

__global__ void scan_k(const int* __restrict__ cnt, int* __restrict__ offs,
                       int* __restrict__ cur) {
  __shared__ int ps[1024];
  const int t = threadIdx.x;
  int loc[12];
  int tot = 0;
#pragma unroll
  for (int j = 0; j < 12; ++j) { loc[j] = tot; tot += cnt[t * 12 + j]; }
  ps[t] = tot;
  __syncthreads();
  for (int d = 1; d < 1024; d <<= 1) {
    int v = (t >= d) ? ps[t - d] : 0;
    __syncthreads();
    ps[t] += v;
    __syncthreads();
  }
  const int base = ps[t] - tot;
#pragma unroll
  for (int j = 0; j < 12; ++j) {
    const int o = base + loc[j];
    offs[t * 12 + j] = o;
    cur[t * 12 + j]  = o;
  }
}

__global__ void sortscat_k(const int* __restrict__ Wc, const int* __restrict__ Rc,
                           const int* __restrict__ Pc, const int* __restrict__ Wr,
                           const int* __restrict__ Rr, const int* __restrict__ Pr,
                           const float* __restrict__ Wv, const float* __restrict__ Rv,
                           const float* __restrict__ Pv, int* __restrict__ cur,
                           float2* __restrict__ packed) {
  const int i = blockIdx.x * blockDim.x + threadIdx.x;
  if (i >= NTOT) return;
  int gc, r; float v;
  if (i < NNZ_W)              { gc = Wc[i];                 r = Wr[i]; v = Wv[i]; }
  else if (i < NNZ_W + NNZ_R) { int j = i - NNZ_W;          gc = HID + Rc[j];     r = Rr[j]; v = Rv[j]; }
  else                        { int j = i - NNZ_W - NNZ_R; gc = 2 * HID + Pc[j]; r = Pr[j]; v = Pv[j]; }
  const int p = atomicAdd(&cur[gc], 1);
  packed[p] = make_float2(v, __int_as_float(r));
}

// ---------------------------------------------------------------------------
// bf16-source column gather, 8 edges in flight:
//   acc[b] = bias + sum_e val_e * bf2f(srcb[row_e][b]).
// One wave per (column, 256-batch chunk); each lane owns 4 consecutive b.
// ---------------------------------------------------------------------------
__device__ __forceinline__ float4 gather_col_bf(const unsigned short* __restrict__ srcb,
                                                const float2* __restrict__ packed,
                                                int beg, int n, int boff, float bias) {
  float4 acc = make_float4(bias, bias, bias, bias);
  const float2* ep = packed + beg;
  int i = 0;
  for (; i + 8 <= n; i += 8) {
    float2 e[8]; ushort4_t s[8];
#pragma unroll
    for (int j = 0; j < 8; ++j) e[j] = ep[i + j];
#pragma unroll
    for (int j = 0; j < 8; ++j)
      s[j] = *(const ushort4_t*)(srcb + (size_t)__float_as_int(e[j].y) * B + boff);
#pragma unroll
    for (int j = 0; j < 8; ++j) {
      acc.x += e[j].x * bf2f(s[j].x);
      acc.y += e[j].x * bf2f(s[j].y);
      acc.z += e[j].x * bf2f(s[j].z);
      acc.w += e[j].x * bf2f(s[j].w);
    }
  }
  for (; i < n; ++i) {
    const float2 e = ep[i];
    const ushort4_t s = *(const ushort4_t*)(srcb + (size_t)__float_as_int(e.y) * B + boff);
    acc.x += e.x * bf2f(s.x);
    acc.y += e.x * bf2f(s.y);
    acc.z += e.x * bf2f(s.z);
    acc.w += e.x * bf2f(s.w);
  }
  return acc;
}

// ---------------------------------------------------------------------------
// Fused: sensory gather (W,bf16) * mask + recurrent gather (R,bf16) -> tanh ->
// leaky integrate (fp32 h_prev carry).  Writes hnT (fp32) + hnb (bf16).
// ---------------------------------------------------------------------------
__global__ void fused_gc_k(const unsigned short* __restrict__ xTb,
                           const unsigned short* __restrict__ hTb,
                           const float* __restrict__ hT,
                           const float2* __restrict__ packed, const int* __restrict__ offs,
                           const int* __restrict__ cnt, const float* __restrict__ rgT,
                           const float* __restrict__ gate, const float* __restrict__ tau,
                           const float* __restrict__ wb, const float* __restrict__ rb,
                           float* __restrict__ hnT, unsigned short* __restrict__ hnb) {
  const int w = blockIdx.x * (blockDim.x >> 6) + (threadIdx.x >> 6);
  const int c = w >> 1;
  const int boff = (w & 1) * 256 + (threadIdx.x & 63) * 4;

  const float4 sens = gather_col_bf(xTb, packed, offs[c], cnt[c], boff, wb[c]);
  const float4 rec  = gather_col_bf(hTb, packed, offs[HID + c], cnt[HID + c], boff, rb[c]);

  const float4 m  = *(const float4*)(rgT + (size_t)(c >> 6) * B + boff);
  const float4 g  = *(const float4*)(gate + boff);
  const float4 hp = *(const float4*)(hT + (size_t)c * B + boff);
  const float k = DT / tau[c];
  float4 hn;
  hn.x = hp.x + g.x * (tanhf(sens.x * m.x + rec.x) - hp.x) * k;
  hn.y = hp.y + g.y * (tanhf(sens.y * m.y + rec.y) - hp.y) * k;
  hn.z = hp.z + g.z * (tanhf(sens.z * m.z + rec.z) - hp.z) * k;
  hn.w = hp.w + g.w * (tanhf(sens.w * m.w + rec.w) - hp.w) * k;
  *(float4*)(hnT + (size_t)c * B + boff) = hn;
  ushort4_t hb;
  hb.x = f2bf(hn.x); hb.y = f2bf(hn.y); hb.z = f2bf(hn.z); hb.w = f2bf(hn.w);
  *(ushort4_t*)(hnb + (size_t)c * B + boff) = hb;
}

// ---------------------------------------------------------------------------
// Prediction gather from h_new (bf16 source).
// ---------------------------------------------------------------------------
__global__ void pred_k(const unsigned short* __restrict__ hnb,
                       const float2* __restrict__ packed,
                       const int* __restrict__ offs, const int* __restrict__ cnt,
                       const float* __restrict__ pb, float* __restrict__ predT) {
  const int w = blockIdx.x * (blockDim.x >> 6) + (threadIdx.x >> 6);
  const int c = w >> 1;
  const int boff = (w & 1) * 256 + (threadIdx.x & 63) * 4;
  const float4 p = gather_col_bf(hnb, packed, offs[2 * HID + c], cnt[2 * HID + c], boff, pb[c]);
  *(float4*)(predT + (size_t)c * B + boff) = p;
}

}  // namespace

extern "C" void kernel_launch(void* const* d_in, const int* in_sizes, int n_in,
                              void* d_out, int out_size, void* d_ws, size_t ws_size,
                              hipStream_t stream) {
  const float* x        = (const float*)d_in[0];
  const float* h_prev   = (const float*)d_in[1];
  const float* gate     = (const float*)d_in[2];
  const float* W_vals   = (const float*)d_in[3];
  const float* W_bias   = (const float*)d_in[4];
  const float* R_vals   = (const float*)d_in[5];
  const float* R_bias   = (const float*)d_in[6];
  const float* P_vals   = (const float*)d_in[7];
  const float* P_bias   = (const float*)d_in[8];
  const float* router_w = (const float*)d_in[9];
  const float* router_b = (const float*)d_in[10];
  const float* tau      = (const float*)d_in[11];
  const int* W_rows = (const int*)d_in[12];
  const int* W_cols = (const int*)d_in[13];
  const int* R_rows = (const int*)d_in[14];
  const int* R_cols = (const int*)d_in[15];
  const int* P_rows = (const int*)d_in[16];
  const int* P_cols = (const int*)d_in[17];

  // Workspace layout (4B units for fp32 parts).
  float* ws = (float*)d_ws;
  unsigned short* xTb = (unsigned short*)ws;                    // [IN][B]  bf16  2 MB
  float*  hT     = ws + (size_t)IN * B / 2;                     // [HID][B] f32   8 MB
  unsigned short* hTb = (unsigned short*)(hT + (size_t)HID * B);// [HID][B] bf16  4 MB
  float*  rgT    = (float*)(hTb + (size_t)HID * B);             // [64][B]  f32
  float*  hnT    = rgT + 64 * B;                                // [HID][B] f32   8 MB
  unsigned short* hnb = (unsigned short*)(hnT + (size_t)HID * B);// [HID][B] bf16 4 MB
  float2* packed = (float2*)(hnb + (size_t)HID * B);            // [NTOT]   3.4 MB
  int*    cnt    = (int*)(packed + NTOT);                       // [NCOLS]
  int*    offs   = cnt + NCOLS;                                 // [NCOLS]
  int*    cur    = offs + NCOLS;                                // [NCOLS]
  float*  predT  = ws;                                          // [HID][B] f32 (reuses xTb+hT, dead after fused)

  float* out_h = (float*)d_out;
  float* out_p = out_h + (size_t)B * HID;

  const dim3 tb(64, 8);
  const int tiles_x = (IN / 64) * (B / 64);    // 256
  const int tiles_h = (HID / 64) * (B / 64);   // 512
  const int tiles_o = (B / 64) * (HID / 64);   // 512 per output

  // 1. Transpose inputs; emit bf16 gather sources (+ fp32 hT for the carry path).
  transpose_in_k<<<tiles_x + tiles_h, tb, 0, stream>>>(x, xTb, h_prev, hT, hTb, tiles_x);

  // 2. Router gates.
  router_k<<<B, 256, 0, stream>>>(x, router_w, router_b, rgT);

  // 3. Bin edges by output column (counting sort) -> gather form, no fp atomics.
  zero_k<<<NCOLS / 256, 256, 0, stream>>>(cnt);
  hist_k<<<(NTOT + 255) / 256, 256, 0, stream>>>(W_cols, R_cols, P_cols, cnt);
  scan_k<<<1, 1024, 0, stream>>>(cnt, offs, cur);
  sortscat_k<<<(NTOT + 255) / 256, 256, 0, stream>>>(W_cols, R_cols, P_cols,
                                                     W_rows, R_rows, P_rows,
                                                     W_vals, R_vals, P_vals, cur, packed);

  // 4. Fused sensory+recurrent gather (bf16 sources), mask, tanh, integrate.
  fused_gc_k<<<HID * 2 / 4, 256, 0, stream>>>(xTb, hTb, hT, packed, offs, cnt, rgT,
                                              gate, tau, W_bias, R_bias, hnT, hnb);

  // 5. Prediction gather from h_new (bf16 source, 4 MB -> L2-resident).
  pred_k<<<HID * 2 / 4, 256, 0, stream>>>(hnb, packed, offs, cnt, P_bias, predT);

  // 6. Transpose both results to row-major outputs.
  transpose_out_k<<<2 * tiles_o, tb, 0, stream>>>(hnT, out_h, tiles_o, predT, out_p);
}

// Round 7
// 142.335 us; speedup vs baseline: 5.2059x; 1.2099x over previous
//
// 5-kernel pipeline: prep (transpose+router+zero) -> slotscat (1-kernel binning,
// 128-slot buckets) -> fused gather (XCD-chunk-split for L2 residency) ->
// pred gather -> output transpose.  bf16 gather sources, fp32 carry/accum.
#include <hip/hip_runtime.h>
#include <math.h>

namespace {

constexpr int B     = 512;
constexpr int IN    = 2048;
constexpr int HID   = 4096;
constexpr int NNZ_W = 83886;
constexpr int NNZ_R = 167772;
constexpr int NTOT  = NNZ_W + 2 * NNZ_R;   // 419430 edges across W,R,P
constexpr int NCOLS = 3 * HID;             // global column id = mat*HID + col
constexpr int SLOT  = 128;                 // per-column bucket capacity
constexpr float DT  = 0.1f;

struct ushort4_t { unsigned short x, y, z, w; };

__device__ __forceinline__ float bf2f(unsigned short u) {
  return __uint_as_float((unsigned int)u << 16);
}
__device__ __forceinline__ unsigned short f2bf(float f) {  // round-nearest-even
  unsigned int u = __float_as_uint(f);
  u += 0x7FFFu + ((u >> 16) & 1u);
  return (unsigned short)(u >> 16);
}

// ---------------------------------------------------------------------------
// prep_k, 512 threads, multi-role by blockIdx.x:
//  [0,256)     transpose x[B][IN]   -> xTb (bf16) [IN][B]
//  [256,768)   transpose h[B][HID]  -> hT (f32) + hTb (bf16) [HID][B]
//  [768,1280)  router row b = blk-768
//  [1280,1304) zero cnt[NCOLS]
// ---------------------------------------------------------------------------
__global__ void prep_k(const float* __restrict__ x, unsigned short* __restrict__ xTb,
                       const float* __restrict__ h, float* __restrict__ hT,
                       unsigned short* __restrict__ hTb,
                       const float* __restrict__ rw, const float* __restrict__ rb,
                       float* __restrict__ rgT, int* __restrict__ cnt) {
  __shared__ float sh[64 * 65];
  const int blk = blockIdx.x;
  const int tid = threadIdx.x;

  if (blk < 768) {                      // --- transpose roles ---
    const bool isX = blk < 256;
    const float* src; int C, tb;
    if (isX) { src = x; C = IN;  tb = blk; }
    else     { src = h; C = HID; tb = blk - 256; }
    const int tx_n = C / 64;
    const int bx = (tb % tx_n) * 64;
    const int by = (tb / tx_n) * 64;
    const int tx = tid & 63;
    const int ty = tid >> 6;            // 0..7
    for (int i = ty; i < 64; i += 8)
      sh[i * 65 + tx] = src[(size_t)(by + i) * C + bx + tx];
    __syncthreads();
    for (int i = ty; i < 64; i += 8) {
      const float v = sh[tx * 65 + i];
      const size_t di = (size_t)(bx + i) * B + by + tx;
      if (isX) xTb[di] = f2bf(v);
      else     { hT[di] = v; hTb[di] = f2bf(v); }
    }
  } else if (blk < 1280) {              // --- router row ---
    const int b = blk - 768;
    for (int k = tid; k < IN; k += 512) sh[k] = x[(size_t)b * IN + k];
    __syncthreads();
    const int o = tid >> 3;             // 0..63
    const int q = tid & 7;              // 0..7
    const float* w  = rw + (size_t)o * IN + q * (IN / 8);
    const float* xp = sh + q * (IN / 8);
    float s = 0.f;
#pragma unroll 8
    for (int k = 0; k < IN / 8; ++k) s += xp[k] * w[k];
    s += __shfl_xor(s, 1);
    s += __shfl_xor(s, 2);
    s += __shfl_xor(s, 4);
    if (q == 0) rgT[o * B + b] = 1.f / (1.f + expf(-(s + rb[o])));
  } else {                              // --- zero cnt ---
    const int i = (blk - 1280) * 512 + tid;
    if (i < NCOLS) cnt[i] = 0;
  }
}

// ---------------------------------------------------------------------------
// One-kernel binning: edge -> (global col bucket, atomic slot).
// packed[gc*SLOT + slot] = (val, row_bits).  cnt[gc] ends as the count.
// ---------------------------------------------------------------------------
__global__ void slotscat_k(const int* __restrict__ Wc, const int* __restrict__ Rc,
                           const int* __restrict__ Pc, const int* __restrict__ Wr,
                           const int* __restrict__ Rr, const int* __restrict__ Pr,
                           const float* __restrict__ Wv, const float* __restrict__ Rv,
                           const float* __restrict__ Pv, int* __restrict__ cnt,
                           float2* __restrict__ packed) {
  const int i = blockIdx.x * blockDim.x + threadIdx.x;
  if (i >= NTOT) return;
  int gc, r; float v;
  if (i < NNZ_W)              { gc = Wc[i];                 r = Wr[i]; v = Wv[i]; }
  else if (i < NNZ_W + NNZ_R) { int j = i - NNZ_W;          gc = HID + Rc[j];     r = Rr[j]; v = Rv[j]; }
  else                        { int j = i - NNZ_W - NNZ_R; gc = 2 * HID + Pc[j]; r = Pr[j]; v = Pv[j]; }
  const int p = atomicAdd(&cnt[gc], 1);
  packed[(size_t)gc * SLOT + p] = make_float2(v, __int_as_float(r));
}

// ---------------------------------------------------------------------------
// bf16-source column gather, 8 edges in flight.
// ---------------------------------------------------------------------------
__device__ __forceinline__ float4 gather_col_bf(const unsigned short* __restrict__ srcb,
                                                const float2* __restrict__ packed,
                                                int gc, int n, int boff, float bias) {
  float4 acc = make_float4(bias, bias, bias, bias);
  const float2* ep = packed + (size_t)gc * SLOT;
  int i = 0;
  for (; i + 8 <= n; i += 8) {
    float2 e[8]; ushort4_t s[8];
#pragma unroll
    for (int j = 0; j < 8; ++j) e[j] = ep[i + j];
#pragma unroll
    for (int j = 0; j < 8; ++j)
      s[j] = *(const ushort4_t*)(srcb + (size_t)__float_as_int(e[j].y) * B + boff);
#pragma unroll
    for (int j = 0; j < 8; ++j) {
      acc.x += e[j].x * bf2f(s[j].x);
      acc.y += e[j].x * bf2f(s[j].y);
      acc.z += e[j].x * bf2f(s[j].z);
      acc.w += e[j].x * bf2f(s[j].w);
    }
  }
  for (; i < n; ++i) {
    const float2 e = ep[i];
    const ushort4_t s = *(const ushort4_t*)(srcb + (size_t)__float_as_int(e.y) * B + boff);
    acc.x += e.x * bf2f(s.x);
    acc.y += e.x * bf2f(s.y);
    acc.z += e.x * bf2f(s.z);
    acc.w += e.x * bf2f(s.w);
  }
  return acc;
}

// XCD-aware decomposition: blk%8 -> XCD (round-robin heuristic).
// XCDs 0-3 own batch chunk 0 (b 0..255), XCDs 4-7 own chunk 1 (b 256..511),
// so each XCD's gather working set is halved (fits 4 MB L2).
__device__ __forceinline__ void col_chunk(int blk, int wave, int& c, int& boff, int lane) {
  const int p = blk & 7;
  const int chunk = p >> 2;
  const int cgrp = ((p & 3) << 8) | (blk >> 3);   // 0..1023
  c = cgrp * 4 + wave;
  boff = chunk * 256 + lane * 4;
}

// ---------------------------------------------------------------------------
// Fused: sensory (W,bf16)*mask + recurrent (R,bf16) -> tanh -> integrate.
// Writes hnT (f32) + hnb (bf16).  Grid 2048 x 256 (4 waves = 4 columns).
// ---------------------------------------------------------------------------
__global__ void fused_gc_k(const unsigned short* __restrict__ xTb,
                           const unsigned short* __restrict__ hTb,
                           const float* __restrict__ hT,
                           const float2* __restrict__ packed, const int* __restrict__ cnt,
                           const float* __restrict__ rgT,
                           const float* __restrict__ gate, const float* __restrict__ tau,
                           const float* __restrict__ wb, const float* __restrict__ rb,
                           float* __restrict__ hnT, unsigned short* __restrict__ hnb) {
  int c, boff;
  col_chunk(blockIdx.x, threadIdx.x >> 6, c, boff, threadIdx.x & 63);

  const float4 sens = gather_col_bf(xTb, packed, c, cnt[c], boff, wb[c]);
  const float4 rec  = gather_col_bf(hTb, packed, HID + c, cnt[HID + c], boff, rb[c]);

  const float4 m  = *(const float4*)(rgT + (size_t)(c >> 6) * B + boff);
  const float4 g  = *(const float4*)(gate + boff);
  const float4 hp = *(const float4*)(hT + (size_t)c * B + boff);
  const float k = DT / tau[c];
  float4 hn;
  hn.x = hp.x + g.x * (tanhf(sens.x * m.x + rec.x) - hp.x) * k;
  hn.y = hp.y + g.y * (tanhf(sens.y * m.y + rec.y) - hp.y) * k;
  hn.z = hp.z + g.z * (tanhf(sens.z * m.z + rec.z) - hp.z) * k;
  hn.w = hp.w + g.w * (tanhf(sens.w * m.w + rec.w) - hp.w) * k;
  *(float4*)(hnT + (size_t)c * B + boff) = hn;
  ushort4_t hb;
  hb.x = f2bf(hn.x); hb.y = f2bf(hn.y); hb.z = f2bf(hn.z); hb.w = f2bf(hn.w);
  *(ushort4_t*)(hnb + (size_t)c * B + boff) = hb;
}

// ---------------------------------------------------------------------------
// Prediction gather from h_new (bf16 source), same XCD-chunk split.
// ---------------------------------------------------------------------------
__global__ void pred_k(const unsigned short* __restrict__ hnb,
                       const float2* __restrict__ packed, const int* __restrict__ cnt,
                       const float* __restrict__ pb, float* __restrict__ predT) {
  int c, boff;
  col_chunk(blockIdx.x, threadIdx.x >> 6, c, boff, threadIdx.x & 63);
  const float4 p = gather_col_bf(hnb, packed, 2 * HID + c, cnt[2 * HID + c], boff, pb[c]);
  *(float4*)(predT + (size_t)c * B + boff) = p;
}

// ---------------------------------------------------------------------------
// Output transpose: two fp32 [HID][B] -> [B][HID] jobs, 512 threads.
// ---------------------------------------------------------------------------
__global__ void transpose_out_k(const float* __restrict__ sA, float* __restrict__ dA,
                                int tilesA, const float* __restrict__ sB,
                                float* __restrict__ dB) {
  __shared__ float t[64][65];
  int tb = blockIdx.x;
  const float* src; float* dst;
  if (tb < tilesA) { src = sA; dst = dA; }
  else             { tb -= tilesA; src = sB; dst = dB; }
  const int tx_n = B / 64;                 // src is [HID][B]
  const int bx = (tb % tx_n) * 64;
  const int by = (tb / tx_n) * 64;
  const int tx = threadIdx.x & 63;
  const int ty = threadIdx.x >> 6;
  for (int i = ty; i < 64; i += 8)
    t[i][tx] = src[(size_t)(by + i) * B + bx + tx];
  __syncthreads();
  for (int i = ty; i < 64; i += 8)
    dst[(size_t)(bx + i) * HID + by + tx] = t[tx][i];
}

}  // namespace

extern "C" void kernel_launch(void* const* d_in, const int* in_sizes, int n_in,
                              void* d_out, int out_size, void* d_ws, size_t ws_size,
                              hipStream_t stream) {
  const float* x        = (const float*)d_in[0];
  const float* h_prev   = (const float*)d_in[1];
  const float* gate     = (const float*)d_in[2];
  const float* W_vals   = (const float*)d_in[3];
  const float* W_bias   = (const float*)d_in[4];
  const float* R_vals   = (const float*)d_in[5];
  const float* R_bias   = (const float*)d_in[6];
  const float* P_vals   = (const float*)d_in[7];
  const float* P_bias   = (const float*)d_in[8];
  const float* router_w = (const float*)d_in[9];
  const float* router_b = (const float*)d_in[10];
  const float* tau      = (const float*)d_in[11];
  const int* W_rows = (const int*)d_in[12];
  const int* W_cols = (const int*)d_in[13];
  const int* R_rows = (const int*)d_in[14];
  const int* R_cols = (const int*)d_in[15];
  const int* P_rows = (const int*)d_in[16];
  const int* P_cols = (const int*)d_in[17];

  float* ws = (float*)d_ws;
  unsigned short* xTb = (unsigned short*)ws;                     // [IN][B]  bf16  2 MB
  float*  hT     = ws + (size_t)IN * B / 2;                      // [HID][B] f32   8 MB
  unsigned short* hTb = (unsigned short*)(hT + (size_t)HID * B); // [HID][B] bf16  4 MB
  float*  rgT    = (float*)(hTb + (size_t)HID * B);              // [64][B]  f32
  float*  hnT    = rgT + 64 * B;                                 // [HID][B] f32   8 MB
  unsigned short* hnb = (unsigned short*)(hnT + (size_t)HID * B);// [HID][B] bf16  4 MB
  float2* packed = (float2*)(hnb + (size_t)HID * B);             // [NCOLS*SLOT]  12.6 MB
  int*    cnt    = (int*)(packed + (size_t)NCOLS * SLOT);        // [NCOLS]
  float*  predT  = ws;   // [HID][B] f32 — reuses xTb+hT region (dead after fused)

  float* out_h = (float*)d_out;
  float* out_p = out_h + (size_t)B * HID;

  // 1. prep: both input transposes + router + cnt zeroing in ONE launch.
  prep_k<<<1304, 512, 0, stream>>>(x, xTb, h_prev, hT, hTb,
                                   router_w, router_b, rgT, cnt);

  // 2. One-kernel binning into fixed 128-slot column buckets.
  slotscat_k<<<(NTOT + 255) / 256, 256, 0, stream>>>(W_cols, R_cols, P_cols,
                                                     W_rows, R_rows, P_rows,
                                                     W_vals, R_vals, P_vals,
                                                     cnt, packed);

  // 3. Fused sensory+recurrent gather, mask, tanh, integrate (XCD-chunk split).
  fused_gc_k<<<2048, 256, 0, stream>>>(xTb, hTb, hT, packed, cnt, rgT,
                                       gate, tau, W_bias, R_bias, hnT, hnb);

  // 4. Prediction gather from h_new.
  pred_k<<<2048, 256, 0, stream>>>(hnb, packed, cnt, P_bias, predT);

  // 5. Transpose both results to row-major outputs.
  transpose_out_k<<<1024, 512, 0, stream>>>(hnT, out_h, 512, predT, out_p);
}

// Round 8
// 114.776 us; speedup vs baseline: 6.4559x; 1.2401x over previous
//
// 5-kernel pipeline; round-8 change: router role rewritten (wave-per-output,
// coalesced rw reads, conflict-free LDS, 4 batch rows per block).
#include <hip/hip_runtime.h>
#include <math.h>

namespace {

constexpr int B     = 512;
constexpr int IN    = 2048;
constexpr int HID   = 4096;
constexpr int NNZ_W = 83886;
constexpr int NNZ_R = 167772;
constexpr int NTOT  = NNZ_W + 2 * NNZ_R;   // 419430 edges across W,R,P
constexpr int NCOLS = 3 * HID;             // global column id = mat*HID + col
constexpr int SLOT  = 128;                 // per-column bucket capacity
constexpr float DT  = 0.1f;

struct ushort4_t { unsigned short x, y, z, w; };

__device__ __forceinline__ float bf2f(unsigned short u) {
  return __uint_as_float((unsigned int)u << 16);
}
__device__ __forceinline__ unsigned short f2bf(float f) {  // round-nearest-even
  unsigned int u = __float_as_uint(f);
  u += 0x7FFFu + ((u >> 16) & 1u);
  return (unsigned short)(u >> 16);
}

// ---------------------------------------------------------------------------
// prep_k, 512 threads, multi-role by blockIdx.x:
//  [0,256)    transpose x[B][IN]  -> xTb (bf16) [IN][B]
//  [256,768)  transpose h[B][HID] -> hT (f32) + hTb (bf16) [HID][B]
//  [768,896)  router: 4 batch rows per block, wave-per-output dot products
//  [896,920)  zero cnt[NCOLS]
// ---------------------------------------------------------------------------
__global__ void prep_k(const float* __restrict__ x, unsigned short* __restrict__ xTb,
                       const float* __restrict__ h, float* __restrict__ hT,
                       unsigned short* __restrict__ hTb,
                       const float* __restrict__ rw, const float* __restrict__ rb,
                       float* __restrict__ rgT, int* __restrict__ cnt) {
  __shared__ float sh[4 * IN];            // 32 KB; transpose uses first 4160
  const int blk = blockIdx.x;
  const int tid = threadIdx.x;

  if (blk < 768) {                        // --- transpose roles ---
    const bool isX = blk < 256;
    const float* src; int C, tb;
    if (isX) { src = x; C = IN;  tb = blk; }
    else     { src = h; C = HID; tb = blk - 256; }
    const int tx_n = C / 64;
    const int bx = (tb % tx_n) * 64;
    const int by = (tb / tx_n) * 64;
    const int tx = tid & 63;
    const int ty = tid >> 6;              // 0..7
    for (int i = ty; i < 64; i += 8)
      sh[i * 65 + tx] = src[(size_t)(by + i) * C + bx + tx];
    __syncthreads();
    for (int i = ty; i < 64; i += 8) {
      const float v = sh[tx * 65 + i];
      const size_t di = (size_t)(bx + i) * B + by + tx;
      if (isX) xTb[di] = f2bf(v);
      else     { hT[di] = v; hTb[di] = f2bf(v); }
    }
  } else if (blk < 896) {                 // --- router: 4 b-rows per block ---
    const int b0 = (blk - 768) * 4;
    // one linear coalesced copy of 4 contiguous rows
    for (int k = tid; k < 4 * IN; k += 512) sh[k] = x[(size_t)b0 * IN + k];
    __syncthreads();
    const int wave = tid >> 6;
    const int lane = tid & 63;
#pragma unroll
    for (int j = 0; j < 8; ++j) {
      const int o = wave * 8 + j;
      const float* w = rw + (size_t)o * IN;
      float s0 = 0.f, s1 = 0.f, s2 = 0.f, s3 = 0.f;
      for (int i = 0; i < IN / 64; ++i) {           // 32 iters
        const float wv = w[lane + 64 * i];          // coalesced 256B
        s0 += sh[0 * IN + lane + 64 * i] * wv;      // conflict-free LDS
        s1 += sh[1 * IN + lane + 64 * i] * wv;
        s2 += sh[2 * IN + lane + 64 * i] * wv;
        s3 += sh[3 * IN + lane + 64 * i] * wv;
      }
#pragma unroll
      for (int d = 1; d < 64; d <<= 1) {
        s0 += __shfl_xor(s0, d);
        s1 += __shfl_xor(s1, d);
        s2 += __shfl_xor(s2, d);
        s3 += __shfl_xor(s3, d);
      }
      if (lane == 0) {
        const float bias = rb[o];
        rgT[o * B + b0 + 0] = 1.f / (1.f + expf(-(s0 + bias)));
        rgT[o * B + b0 + 1] = 1.f / (1.f + expf(-(s1 + bias)));
        rgT[o * B + b0 + 2] = 1.f / (1.f + expf(-(s2 + bias)));
        rgT[o * B + b0 + 3] = 1.f / (1.f + expf(-(s3 + bias)));
      }
    }
  } else {                                // --- zero cnt ---
    const int i = (blk - 896) * 512 + tid;
    if (i < NCOLS) cnt[i] = 0;
  }
}

// ---------------------------------------------------------------------------
// One-kernel binning: edge -> (global col bucket, atomic slot).
// packed[gc*SLOT + slot] = (val, row_bits).  cnt[gc] ends as the count.
// ---------------------------------------------------------------------------
__global__ void slotscat_k(const int* __restrict__ Wc, const int* __restrict__ Rc,
                           const int* __restrict__ Pc, const int* __restrict__ Wr,
                           const int* __restrict__ Rr, const int* __restrict__ Pr,
                           const float* __restrict__ Wv, const float* __restrict__ Rv,
                           const float* __restrict__ Pv, int* __restrict__ cnt,
                           float2* __restrict__ packed) {
  const int i = blockIdx.x * blockDim.x + threadIdx.x;
  if (i >= NTOT) return;
  int gc, r; float v;
  if (i < NNZ_W)              { gc = Wc[i];                 r = Wr[i]; v = Wv[i]; }
  else if (i < NNZ_W + NNZ_R) { int j = i - NNZ_W;          gc = HID + Rc[j];     r = Rr[j]; v = Rv[j]; }
  else                        { int j = i - NNZ_W - NNZ_R; gc = 2 * HID + Pc[j]; r = Pr[j]; v = Pv[j]; }
  const int p = atomicAdd(&cnt[gc], 1);
  packed[(size_t)gc * SLOT + p] = make_float2(v, __int_as_float(r));
}

// ---------------------------------------------------------------------------
// bf16-source column gather, 8 edges in flight.
// ---------------------------------------------------------------------------
__device__ __forceinline__ float4 gather_col_bf(const unsigned short* __restrict__ srcb,
                                                const float2* __restrict__ packed,
                                                int gc, int n, int boff, float bias) {
  float4 acc = make_float4(bias, bias, bias, bias);
  const float2* ep = packed + (size_t)gc * SLOT;
  int i = 0;
  for (; i + 8 <= n; i += 8) {
    float2 e[8]; ushort4_t s[8];
#pragma unroll
    for (int j = 0; j < 8; ++j) e[j] = ep[i + j];
#pragma unroll
    for (int j = 0; j < 8; ++j)
      s[j] = *(const ushort4_t*)(srcb + (size_t)__float_as_int(e[j].y) * B + boff);
#pragma unroll
    for (int j = 0; j < 8; ++j) {
      acc.x += e[j].x * bf2f(s[j].x);
      acc.y += e[j].x * bf2f(s[j].y);
      acc.z += e[j].x * bf2f(s[j].z);
      acc.w += e[j].x * bf2f(s[j].w);
    }
  }
  for (; i < n; ++i) {
    const float2 e = ep[i];
    const ushort4_t s = *(const ushort4_t*)(srcb + (size_t)__float_as_int(e.y) * B + boff);
    acc.x += e.x * bf2f(s.x);
    acc.y += e.x * bf2f(s.y);
    acc.z += e.x * bf2f(s.z);
    acc.w += e.x * bf2f(s.w);
  }
  return acc;
}

// XCD-aware decomposition: blk%8 -> XCD (round-robin heuristic).
// XCDs 0-3 own batch chunk 0 (b 0..255), XCDs 4-7 own chunk 1 (b 256..511),
// so each XCD's gather working set is halved (fits 4 MB L2).
__device__ __forceinline__ void col_chunk(int blk, int wave, int& c, int& boff, int lane) {
  const int p = blk & 7;
  const int chunk = p >> 2;
  const int cgrp = ((p & 3) << 8) | (blk >> 3);   // 0..1023
  c = cgrp * 4 + wave;
  boff = chunk * 256 + lane * 4;
}

// ---------------------------------------------------------------------------
// Fused: sensory (W,bf16)*mask + recurrent (R,bf16) -> tanh -> integrate.
// Writes hnT (f32) + hnb (bf16).  Grid 2048 x 256 (4 waves = 4 columns).
// ---------------------------------------------------------------------------
__global__ void fused_gc_k(const unsigned short* __restrict__ xTb,
                           const unsigned short* __restrict__ hTb,
                           const float* __restrict__ hT,
                           const float2* __restrict__ packed, const int* __restrict__ cnt,
                           const float* __restrict__ rgT,
                           const float* __restrict__ gate, const float* __restrict__ tau,
                           const float* __restrict__ wb, const float* __restrict__ rb,
                           float* __restrict__ hnT, unsigned short* __restrict__ hnb) {
  int c, boff;
  col_chunk(blockIdx.x, threadIdx.x >> 6, c, boff, threadIdx.x & 63);

  const float4 sens = gather_col_bf(xTb, packed, c, cnt[c], boff, wb[c]);
  const float4 rec  = gather_col_bf(hTb, packed, HID + c, cnt[HID + c], boff, rb[c]);

  const float4 m  = *(const float4*)(rgT + (size_t)(c >> 6) * B + boff);
  const float4 g  = *(const float4*)(gate + boff);
  const float4 hp = *(const float4*)(hT + (size_t)c * B + boff);
  const float k = DT / tau[c];
  float4 hn;
  hn.x = hp.x + g.x * (tanhf(sens.x * m.x + rec.x) - hp.x) * k;
  hn.y = hp.y + g.y * (tanhf(sens.y * m.y + rec.y) - hp.y) * k;
  hn.z = hp.z + g.z * (tanhf(sens.z * m.z + rec.z) - hp.z) * k;
  hn.w = hp.w + g.w * (tanhf(sens.w * m.w + rec.w) - hp.w) * k;
  *(float4*)(hnT + (size_t)c * B + boff) = hn;
  ushort4_t hb;
  hb.x = f2bf(hn.x); hb.y = f2bf(hn.y); hb.z = f2bf(hn.z); hb.w = f2bf(hn.w);
  *(ushort4_t*)(hnb + (size_t)c * B + boff) = hb;
}

// ---------------------------------------------------------------------------
// Prediction gather from h_new (bf16 source), same XCD-chunk split.
// ---------------------------------------------------------------------------
__global__ void pred_k(const unsigned short* __restrict__ hnb,
                       const float2* __restrict__ packed, const int* __restrict__ cnt,
                       const float* __restrict__ pb, float* __restrict__ predT) {
  int c, boff;
  col_chunk(blockIdx.x, threadIdx.x >> 6, c, boff, threadIdx.x & 63);
  const float4 p = gather_col_bf(hnb, packed, 2 * HID + c, cnt[2 * HID + c], boff, pb[c]);
  *(float4*)(predT + (size_t)c * B + boff) = p;
}

// ---------------------------------------------------------------------------
// Output transpose: two fp32 [HID][B] -> [B][HID] jobs, 512 threads.
// ---------------------------------------------------------------------------
__global__ void transpose_out_k(const float* __restrict__ sA, float* __restrict__ dA,
                                int tilesA, const float* __restrict__ sB,
                                float* __restrict__ dB) {
  __shared__ float t[64][65];
  int tb = blockIdx.x;
  const float* src; float* dst;
  if (tb < tilesA) { src = sA; dst = dA; }
  else             { tb -= tilesA; src = sB; dst = dB; }
  const int tx_n = B / 64;                 // src is [HID][B]
  const int bx = (tb % tx_n) * 64;
  const int by = (tb / tx_n) * 64;
  const int tx = threadIdx.x & 63;
  const int ty = threadIdx.x >> 6;
  for (int i = ty; i < 64; i += 8)
    t[i][tx] = src[(size_t)(by + i) * B + bx + tx];
  __syncthreads();
  for (int i = ty; i < 64; i += 8)
    dst[(size_t)(bx + i) * HID + by + tx] = t[tx][i];
}

}  // namespace

extern "C" void kernel_launch(void* const* d_in, const int* in_sizes, int n_in,
                              void* d_out, int out_size, void* d_ws, size_t ws_size,
                              hipStream_t stream) {
  const float* x        = (const float*)d_in[0];
  const float* h_prev   = (const float*)d_in[1];
  const float* gate     = (const float*)d_in[2];
  const float* W_vals   = (const float*)d_in[3];
  const float* W_bias   = (const float*)d_in[4];
  const float* R_vals   = (const float*)d_in[5];
  const float* R_bias   = (const float*)d_in[6];
  const float* P_vals   = (const float*)d_in[7];
  const float* P_bias   = (const float*)d_in[8];
  const float* router_w = (const float*)d_in[9];
  const float* router_b = (const float*)d_in[10];
  const float* tau      = (const float*)d_in[11];
  const int* W_rows = (const int*)d_in[12];
  const int* W_cols = (const int*)d_in[13];
  const int* R_rows = (const int*)d_in[14];
  const int* R_cols = (const int*)d_in[15];
  const int* P_rows = (const int*)d_in[16];
  const int* P_cols = (const int*)d_in[17];

  float* ws = (float*)d_ws;
  unsigned short* xTb = (unsigned short*)ws;                     // [IN][B]  bf16  2 MB
  float*  hT     = ws + (size_t)IN * B / 2;                      // [HID][B] f32   8 MB
  unsigned short* hTb = (unsigned short*)(hT + (size_t)HID * B); // [HID][B] bf16  4 MB
  float*  rgT    = (float*)(hTb + (size_t)HID * B);              // [64][B]  f32
  float*  hnT    = rgT + 64 * B;                                 // [HID][B] f32   8 MB
  unsigned short* hnb = (unsigned short*)(hnT + (size_t)HID * B);// [HID][B] bf16  4 MB
  float2* packed = (float2*)(hnb + (size_t)HID * B);             // [NCOLS*SLOT]  12.6 MB
  int*    cnt    = (int*)(packed + (size_t)NCOLS * SLOT);        // [NCOLS]
  float*  predT  = ws;   // [HID][B] f32 — reuses xTb+hT region (dead after fused)

  float* out_h = (float*)d_out;
  float* out_p = out_h + (size_t)B * HID;

  // 1. prep: input transposes + router (fixed) + cnt zeroing in ONE launch.
  prep_k<<<920, 512, 0, stream>>>(x, xTb, h_prev, hT, hTb,
                                  router_w, router_b, rgT, cnt);

  // 2. One-kernel binning into fixed 128-slot column buckets.
  slotscat_k<<<(NTOT + 255) / 256, 256, 0, stream>>>(W_cols, R_cols, P_cols,
                                                     W_rows, R_rows, P_rows,
                                                     W_vals, R_vals, P_vals,
                                                     cnt, packed);

  // 3. Fused sensory+recurrent gather, mask, tanh, integrate (XCD-chunk split).
  fused_gc_k<<<2048, 256, 0, stream>>>(xTb, hTb, hT, packed, cnt, rgT,
                                       gate, tau, W_bias, R_bias, hnT, hnb);

  // 4. Prediction gather from h_new.
  pred_k<<<2048, 256, 0, stream>>>(hnb, packed, cnt, P_bias, predT);

  // 5. Transpose both results to row-major outputs.
  transpose_out_k<<<1024, 512, 0, stream>>>(hnT, out_h, 512, predT, out_p);
}